// Round 1
// baseline (2106.341 us; speedup 1.0000x reference)
//
#include <hip/hip_runtime.h>
#include <cstdint>
#include <math.h>

#define B_  64
#define L_  256
#define V_  256
#define E_  256
#define H_  1024
#define H3  3072

typedef __bf16 bf16x8 __attribute__((ext_vector_type(8)));
typedef float  f32x4  __attribute__((ext_vector_type(4)));

__device__ __forceinline__ unsigned short f2bf(float f) {
    union { float f; unsigned u; } v; v.f = f;
    unsigned r = v.u + 0x7fffu + ((v.u >> 16) & 1u);   // round-to-nearest-even
    return (unsigned short)(r >> 16);
}
__device__ __forceinline__ float bf2f(unsigned short u) {
    union { unsigned u; float f; } v; v.u = ((unsigned)u) << 16;
    return v.f;
}

// ---- prep: fp32 [rows][cols] -> bf16 [cols][rows] (N-major for B-fragments) ----
__global__ void prep_transpose(const float* __restrict__ src,
                               unsigned short* __restrict__ dst,
                               int rows, int cols) {
    int idx = blockIdx.x * 256 + threadIdx.x;
    if (idx >= rows * cols) return;
    int n = idx / rows;      // output row  (source col)
    int k = idx % rows;      // output col  (source row)
    dst[idx] = f2bf(src[(size_t)k * cols + n]);
}

// ---- prep: embedding fp32->bf16 + zero initial hidden state ----
__global__ void prep_misc(const float* __restrict__ emb,
                          unsigned short* __restrict__ embB,
                          float* __restrict__ h0f,
                          unsigned short* __restrict__ h0b) {
    int idx = blockIdx.x * 256 + threadIdx.x;   // 65536 = V*E = B*H
    embB[idx] = f2bf(emb[idx]);
    h0f[idx]  = 0.0f;
    h0b[idx]  = 0;
}

// ---- phase 1: xw[m][3H] = emb[tok[m]] @ Wi   (M=16384, K=256, N=3072) ----
__global__ __launch_bounds__(256) void xw_gemm(const int* __restrict__ tokens,
                                               const unsigned short* __restrict__ embB,
                                               const unsigned short* __restrict__ WiT,
                                               unsigned short* __restrict__ xw) {
    int ntile = blockIdx.x;          // 48 tiles of 64 cols
    int mtile = blockIdx.y;          // 256 tiles of 64 rows
    int wave = threadIdx.x >> 6, lane = threadIdx.x & 63;
    int l16 = lane & 15, q = lane >> 4;

    int m = mtile * 64 + wave * 16 + l16;    // A row (m = lane&15 within tile)
    int tok = tokens[m];
    const bf16x8* Arow = (const bf16x8*)(embB + (size_t)tok * E_);
    int n0 = ntile * 64;

    f32x4 acc[4] = {};
    for (int k0 = 0; k0 < E_; k0 += 32) {
        bf16x8 a = Arow[(k0 >> 3) + q];      // k = k0 + q*8 .. +7
#pragma unroll
        for (int j = 0; j < 4; j++) {
            const bf16x8* Brow = (const bf16x8*)(WiT + (size_t)(n0 + j*16 + l16) * E_);
            bf16x8 b = Brow[(k0 >> 3) + q];
            acc[j] = __builtin_amdgcn_mfma_f32_16x16x32_bf16(a, b, acc[j], 0, 0, 0);
        }
    }
    // C layout: col = lane&15, row = q*4 + r
    int mrow = mtile * 64 + wave * 16 + q * 4;
#pragma unroll
    for (int j = 0; j < 4; j++) {
        int n = n0 + j * 16 + l16;
#pragma unroll
        for (int r = 0; r < 4; r++)
            xw[(size_t)(mrow + r) * H3 + n] = f2bf(acc[j][r]);
    }
}

// ---- phase 2: one GRU step.  grid = (64 jtiles, 4 btiles), block = 256 ----
__global__ __launch_bounds__(256) void gru_step(const unsigned short* __restrict__ hb_in,
                                                const float* __restrict__ hf_in,
                                                unsigned short* __restrict__ hb_out,
                                                float* __restrict__ hf_out,
                                                const unsigned short* __restrict__ WhT,
                                                const float* __restrict__ bh,
                                                const unsigned short* __restrict__ xw,
                                                unsigned short* __restrict__ yB,
                                                int t) {
    __shared__ f32x4 red[4][3][64];
    int jtile = blockIdx.x;          // 64 tiles of 16 h-cols
    int btile = blockIdx.y;          // 4 tiles of 16 batches
    int wave = threadIdx.x >> 6, lane = threadIdx.x & 63;
    int l16 = lane & 15, q = lane >> 4;
    int b0 = btile * 16, j0 = jtile * 16;

    const bf16x8* Arow = (const bf16x8*)(hb_in + (size_t)(b0 + l16) * H_);
    f32x4 acc[3] = {};
    int kbase = wave * 256;          // K split across the 4 waves
#pragma unroll
    for (int kk = 0; kk < 8; kk++) {
        int k = kbase + kk * 32 + q * 8;
        bf16x8 a = Arow[k >> 3];
#pragma unroll
        for (int g = 0; g < 3; g++) {
            const bf16x8* Brow = (const bf16x8*)(WhT + (size_t)(g * H_ + j0 + l16) * H_);
            bf16x8 b = Brow[k >> 3];
            acc[g] = __builtin_amdgcn_mfma_f32_16x16x32_bf16(a, b, acc[g], 0, 0, 0);
        }
    }
#pragma unroll
    for (int g = 0; g < 3; g++) red[wave][g][lane] = acc[g];
    __syncthreads();

    // cross-wave K reduction + fused gates: thread t -> (L = lane pattern, reg)
    int Lp  = threadIdx.x & 63;
    int reg = threadIdx.x >> 6;
    float gh0 = red[0][0][Lp][reg] + red[1][0][Lp][reg] + red[2][0][Lp][reg] + red[3][0][Lp][reg];
    float gh1 = red[0][1][Lp][reg] + red[1][1][Lp][reg] + red[2][1][Lp][reg] + red[3][1][Lp][reg];
    float gh2 = red[0][2][Lp][reg] + red[1][2][Lp][reg] + red[2][2][Lp][reg] + red[3][2][Lp][reg];

    int b_local = (Lp >> 4) * 4 + reg;   // C row
    int j_local = Lp & 15;               // C col
    int b = b0 + b_local, jg = j0 + j_local;

    float ghr = gh0 + bh[jg];
    float ghz = gh1 + bh[H_ + jg];
    float ghn = gh2 + bh[2 * H_ + jg];

    size_t xoff = ((size_t)b * L_ + t) * H3;
    float xr = bf2f(xw[xoff + jg]);
    float xz = bf2f(xw[xoff + H_ + jg]);
    float xn = bf2f(xw[xoff + 2 * H_ + jg]);

    float r = 1.0f / (1.0f + __expf(-(xr + ghr)));
    float z = 1.0f / (1.0f + __expf(-(xz + ghz)));
    float n = tanhf(xn + r * ghn);
    float hold = hf_in[(size_t)b * H_ + jg];
    float hnew = (1.0f - z) * n + z * hold;

    hf_out[(size_t)b * H_ + jg] = hnew;
    unsigned short hb = f2bf(hnew);
    hb_out[(size_t)b * H_ + jg] = hb;
    yB[((size_t)b * L_ + t) * H_ + jg] = hb;
}

// ---- phase 3: logits[m][v] = y[m] @ Wout + bout   (M=16384, K=1024, N=256) ----
__global__ __launch_bounds__(256) void out_gemm(const unsigned short* __restrict__ yB,
                                                const unsigned short* __restrict__ WoutT,
                                                const float* __restrict__ bout,
                                                float* __restrict__ out) {
    int ntile = blockIdx.x;          // 4 tiles of 64 cols
    int mtile = blockIdx.y;          // 256 tiles of 64 rows
    int wave = threadIdx.x >> 6, lane = threadIdx.x & 63;
    int l16 = lane & 15, q = lane >> 4;

    int m = mtile * 64 + wave * 16 + l16;
    const bf16x8* Arow = (const bf16x8*)(yB + (size_t)m * H_);
    int n0 = ntile * 64;

    f32x4 acc[4] = {};
    for (int k0 = 0; k0 < H_; k0 += 32) {
        bf16x8 a = Arow[(k0 >> 3) + q];
#pragma unroll
        for (int j = 0; j < 4; j++) {
            const bf16x8* Brow = (const bf16x8*)(WoutT + (size_t)(n0 + j*16 + l16) * H_);
            bf16x8 b = Brow[(k0 >> 3) + q];
            acc[j] = __builtin_amdgcn_mfma_f32_16x16x32_bf16(a, b, acc[j], 0, 0, 0);
        }
    }
    int mrow = mtile * 64 + wave * 16 + q * 4;
#pragma unroll
    for (int j = 0; j < 4; j++) {
        int n = n0 + j * 16 + l16;
        float bias = bout[n];
#pragma unroll
        for (int r = 0; r < 4; r++)
            out[(size_t)(mrow + r) * V_ + n] = acc[j][r] + bias;
    }
}

extern "C" void kernel_launch(void* const* d_in, const int* in_sizes, int n_in,
                              void* d_out, int out_size, void* d_ws, size_t ws_size,
                              hipStream_t stream) {
    const int*   tokens = (const int*)  d_in[0];
    const float* emb    = (const float*)d_in[1];
    const float* Wi     = (const float*)d_in[2];
    const float* Wh     = (const float*)d_in[3];
    const float* bh     = (const float*)d_in[4];
    const float* Wout   = (const float*)d_in[5];
    const float* bout   = (const float*)d_in[6];
    float* out = (float*)d_out;

    char* ws = (char*)d_ws;
    size_t off = 0;
    auto alloc = [&](size_t bytes) -> void* {
        void* p = ws + off;
        off += (bytes + 255) & ~(size_t)255;
        return p;
    };
    unsigned short* WhT   = (unsigned short*)alloc((size_t)H3 * H_ * 2);   // [3072][1024]
    unsigned short* WiT   = (unsigned short*)alloc((size_t)H3 * E_ * 2);   // [3072][256]
    unsigned short* WoutT = (unsigned short*)alloc((size_t)V_ * H_ * 2);   // [256][1024]
    unsigned short* embB  = (unsigned short*)alloc((size_t)V_ * E_ * 2);   // [256][256]
    unsigned short* xw    = (unsigned short*)alloc((size_t)B_ * L_ * H3 * 2); // 96 MB
    unsigned short* yB    = (unsigned short*)alloc((size_t)B_ * L_ * H_ * 2); // 32 MB
    float*          hf0   = (float*)alloc((size_t)B_ * H_ * 4);
    float*          hf1   = (float*)alloc((size_t)B_ * H_ * 4);
    unsigned short* hb0   = (unsigned short*)alloc((size_t)B_ * H_ * 2);
    unsigned short* hb1   = (unsigned short*)alloc((size_t)B_ * H_ * 2);
    float*          hf[2] = {hf0, hf1};
    unsigned short* hb[2] = {hb0, hb1};

    prep_transpose<<<(H_ * H3 + 255) / 256, 256, 0, stream>>>(Wh, WhT, H_, H3);
    prep_transpose<<<(E_ * H3 + 255) / 256, 256, 0, stream>>>(Wi, WiT, E_, H3);
    prep_transpose<<<(H_ * V_ + 255) / 256, 256, 0, stream>>>(Wout, WoutT, H_, V_);
    prep_misc<<<(B_ * H_) / 256, 256, 0, stream>>>(emb, embB, hf[0], hb[0]);

    xw_gemm<<<dim3(48, 256), 256, 0, stream>>>(tokens, embB, WiT, xw);

    for (int t = 0; t < L_; t++) {
        int in = t & 1, ob = in ^ 1;
        gru_step<<<dim3(64, 4), 256, 0, stream>>>(hb[in], hf[in], hb[ob], hf[ob],
                                                  WhT, bh, xw, yB, t);
    }

    out_gemm<<<dim3(4, 256), 256, 0, stream>>>(yB, WoutT, bout, out);
}